// Round 1
// 2356.282 us; speedup vs baseline: 1.0263x; 1.0263x over previous
//
#include <hip/hip_runtime.h>
#include <math.h>

// KanLayer: out[o] = sum_i sum_k c[i,o,k] * B[i,k]
// x: (2048,) fp32 in [0,1); c: (2048, 4096, 61) fp32; out: (4096,) fp32.
// B is a degree-2 B-spline basis: each row B[i,:] has <=3 nonzeros at
// k = j-2..j (t_j <= x_i < t_{j+1}), right-edge truncated.
//
// This version: one global_load_dwordx4 per (i,o) chunk (covers k0..k0+3,
// 4th weight zeroed; k0 clamped to <=57 so the 16B read stays inside the
// 61-float row -> no OOB). Loads are issued as an explicit 16-deep gather
// phase before the FMA phase to maximize loads-in-flight per wave
// (the previous 48x interleaved dword version was latency-serialized).

#define INPUT_DIM 2048
#define OUT_DIM   4096
#define N_COEF    61
#define IC        16    // i's per block (grid.y = 2048/16 = 128)
#define OB        256   // o's per block (grid.x = 4096/256 = 16)

__device__ __forceinline__ float Tk(int k) {
    // matches jnp.linspace(-1, 1, 64) to within 1 ulp
    return -1.0f + (float)k * (2.0f / 63.0f);
}

__global__ void kan_zero_kernel(float* __restrict__ out) {
    out[blockIdx.x * blockDim.x + threadIdx.x] = 0.0f;
}

__global__ __launch_bounds__(OB) void kan_kernel(const float* __restrict__ x,
                                                 const float* __restrict__ c,
                                                 float* __restrict__ out) {
    __shared__ int    sk0[IC];
    __shared__ float4 sw[IC];

    const int tid    = threadIdx.x;
    const int i_base = blockIdx.y * IC;

    if (tid < IC) {
        const float xv = x[i_base + tid];
        // interval index j: t_j <= xv < t_{j+1}
        int j = (int)floorf((xv + 1.0f) * 31.5f);
        j = max(0, min(62, j));
        while (j > 0  && xv <  Tk(j))     --j;   // <=1 iter fixups
        while (j < 62 && xv >= Tk(j + 1)) ++j;

        const float tjm1 = Tk(j - 1), tj = Tk(j), tj1 = Tk(j + 1), tj2 = Tk(j + 2);
        // Cox-de Boor, degree 1 then degree 2:
        const float b1l = (tj1 - xv) / (tj1 - tj);   // B1_{j-1}
        const float b1r = (xv - tj)  / (tj1 - tj);   // B1_j
        const float w0 = (tj1 - xv) / (tj1 - tjm1) * b1l;                       // B2_{j-2}
        const float w1 = (xv - tjm1) / (tj1 - tjm1) * b1l
                       + (tj2 - xv) / (tj2 - tj)    * b1r;                      // B2_{j-1}
        const float w2 = (xv - tj)  / (tj2 - tj)    * b1r;                      // B2_j

        // Place the 3 weights inside a 4-wide window [k0, k0+3] with
        // k0 <= 57 (so k0+3 <= 60: the dwordx4 never crosses the row end)
        // and k0 >= 0. Weights whose k falls outside [0,60] or outside the
        // window are dropped (they correspond to truncated basis entries).
        int s = j - 59; if (s < 0) s = 0;
        int k0 = j - 2 - s; if (k0 < 0) k0 = 0;
        const float wsrc[3] = {w0, w1, w2};
        float ww[4] = {0.0f, 0.0f, 0.0f, 0.0f};
        #pragma unroll
        for (int m = 0; m < 3; ++m) {
            const int l = (j - 2 + m) - k0;
            if (0 <= l && l < 4) ww[l] = wsrc[m];
        }
        sk0[tid] = k0;
        sw[tid]  = make_float4(ww[0], ww[1], ww[2], ww[3]);
    }
    __syncthreads();

    const int o = blockIdx.x * OB + tid;
    const long long stride_i = (long long)OUT_DIM * N_COEF;  // 249856
    const float* pbase = c + (long long)i_base * stride_i + (long long)o * N_COEF;

    // Phase 1: issue all 16 scattered 16B gathers (one dwordx4 per i).
    // gfx950 global_load_dwordx4 requires only dword alignment, which the
    // float* arithmetic guarantees.
    float4 d[IC];
    #pragma unroll
    for (int ii = 0; ii < IC; ++ii) {
        const float* p = pbase + (long long)ii * stride_i + sk0[ii];
        d[ii] = *reinterpret_cast<const float4*>(p);
    }

    // Phase 2: FMA with the padded weights (w-lane weight is 0 unless the
    // right-edge shift moved real weights there).
    float acc = 0.0f;
    #pragma unroll
    for (int ii = 0; ii < IC; ++ii) {
        const float4 w = sw[ii];
        acc = fmaf(d[ii].x, w.x, acc);
        acc = fmaf(d[ii].y, w.y, acc);
        acc = fmaf(d[ii].z, w.z, acc);
        acc = fmaf(d[ii].w, w.w, acc);
    }
    atomicAdd(&out[o], acc);
}

extern "C" void kernel_launch(void* const* d_in, const int* in_sizes, int n_in,
                              void* d_out, int out_size, void* d_ws, size_t ws_size,
                              hipStream_t stream) {
    const float* x   = (const float*)d_in[0];
    const float* c   = (const float*)d_in[1];
    float*       out = (float*)d_out;

    hipLaunchKernelGGL(kan_zero_kernel, dim3(OUT_DIM / 256), dim3(256), 0, stream, out);

    dim3 grid(OUT_DIM / OB, INPUT_DIM / IC);   // 16 x 128 = 2048 blocks
    hipLaunchKernelGGL(kan_kernel, grid, dim3(OB), 0, stream, x, c, out);
}